// Round 1
// baseline (504.090 us; speedup 1.0000x reference)
//
#include <hip/hip_runtime.h>
#include <math.h>

#define BB 64
#define TT 256
#define VV 256

// logaddexp, robust to -inf operands
__device__ __forceinline__ float lae(float x, float y) {
    float m = fmaxf(x, y);
    if (m == -INFINITY) return -INFINITY;
    float n = fminf(x, y);
    return m + __logf(1.0f + __expf(n - m));
}

// Kernel 1: log_softmax over the class dim (C=4) — one float4 per cell.
__global__ void k_logsoftmax(const float4* __restrict__ lg, float4* __restrict__ sc, int n) {
    int i = blockIdx.x * blockDim.x + threadIdx.x;
    int st = gridDim.x * blockDim.x;
    for (; i < n; i += st) {
        float4 x = lg[i];
        float m = fmaxf(fmaxf(x.x, x.y), fmaxf(x.z, x.w));
        float s = __expf(x.x - m) + __expf(x.y - m) + __expf(x.z - m) + __expf(x.w - m);
        float l = m + __logf(s);
        sc[i] = make_float4(x.x - l, x.y - l, x.z - l, x.w - l);
    }
}

// Fused counts epilogue for row t: softmax over the 3 masked edge terms.
// beta cancels between ec and norm, so it is omitted entirely.
__device__ __forceinline__ void write_counts(int t, int v0,
        const float4* scur, const float* aPrev, const float* aCur,
        float4* __restrict__ crow) {
    float upP = __shfl_up(aPrev[3], 1);
    float upC = __shfl_up(aCur[3], 1);
    float aPm1[4] = { upP, aPrev[0], aPrev[1], aPrev[2] };
    float aCm1[4] = { upC, aCur[0], aCur[1], aCur[2] };
    bool valid0 = (t >= 1) && (t < TT - 1);
#pragma unroll
    for (int k = 0; k < 4; ++k) {
        int v = v0 + k;
        bool valid1 = (v >= 1) && (v < VV - 1);
        float e0 = valid0 ? aPrev[k] + scur[k].x : -INFINITY;             // delete
        float e1 = valid1 ? aCm1[k] + scur[k].y : -INFINITY;             // insert
        float e2 = (valid0 && valid1) ? aPm1[k] + scur[k].z : -INFINITY; // sub
        float m = fmaxf(e0, fmaxf(e1, e2));
        float4 o = make_float4(0.0f, 0.0f, 0.0f, 0.0f);
        if (m != -INFINITY) {
            float w0 = __expf(e0 - m);
            float w1 = __expf(e1 - m);
            float w2 = __expf(e2 - m);
            float r = 1.0f / (w0 + w1 + w2);
            o = make_float4(w0 * r, w1 * r, w2 * r, 0.0f);
        }
        crow[(size_t)t * VV + v] = o;
    }
}

// Kernel 2: per-batch forward DP. One wave (64 lanes) per batch, 4 columns per
// lane. Row recurrence x[v] = lae(x[v-1]+ins[v], c[v]) is an affine log-space
// recurrence -> wave-level scan with compose (A1,C1)o(A2,C2)=(A1+A2, lae(C1+A2,C2)).
__global__ void __launch_bounds__(64) k_dp(const float4* __restrict__ scores,
                                           float4* __restrict__ counts,
                                           float* __restrict__ scalar_out) {
    const int b = blockIdx.x;
    const int lane = threadIdx.x;  // 0..63
    const int v0 = lane << 2;

    const float4* srow = scores + (size_t)b * TT * VV;
    float4* crow = counts + (size_t)b * TT * VV;

    float4 sc[4], sn[4];
#pragma unroll
    for (int k = 0; k < 4; ++k) sc[k] = srow[v0 + k];           // row 0
#pragma unroll
    for (int k = 0; k < 4; ++k) sn[k] = srow[VV + v0 + k];      // prefetch row 1

    float aPrev[4], aCur[4];

    // alpha row 0: prefix sum of ins (class 1), with g[0] = 0
    {
        float l0 = (v0 == 0) ? 0.0f : sc[0].y;
        float l1 = l0 + sc[1].y;
        float l2 = l1 + sc[2].y;
        float l3 = l2 + sc[3].y;
        float A = l3;
#pragma unroll
        for (int off = 1; off < 64; off <<= 1) {
            float o = __shfl_up(A, off);
            if (lane >= off) A += o;
        }
        float ex = __shfl_up(A, 1);
        float carry = (lane == 0) ? 0.0f : ex;
        aCur[0] = carry + l0; aCur[1] = carry + l1;
        aCur[2] = carry + l2; aCur[3] = carry + l3;
    }
    // counts row 0 (only insert class can be valid; aPrev terms are masked out)
#pragma unroll
    for (int k = 0; k < 4; ++k) aPrev[k] = aCur[k];
    write_counts(0, v0, sc, aPrev, aCur, crow);

#pragma unroll 1
    for (int t = 1; t < TT; ++t) {
        float4 scur[4];
#pragma unroll
        for (int k = 0; k < 4; ++k) scur[k] = sn[k];
        if (t + 1 < TT) {
#pragma unroll
            for (int k = 0; k < 4; ++k) sn[k] = srow[(size_t)(t + 1) * VV + v0 + k];
        }
        // c[v] = lae(del[v] + aPrev[v], sub[v] + aPrev[v-1]);  c[0] = del[0]+aPrev[0]
        float upP = __shfl_up(aPrev[3], 1);
        float aPm1[4] = { upP, aPrev[0], aPrev[1], aPrev[2] };
        float cv[4], ia[4];
#pragma unroll
        for (int k = 0; k < 4; ++k) {
            ia[k] = scur[k].y;
            float cd = scur[k].x + aPrev[k];
            float cs = scur[k].z + aPm1[k];
            cv[k] = lae(cd, cs);
        }
        if (lane == 0) cv[0] = scur[0].x + aPrev[0];

        // lane-local compose of the 4 elements
        float A = ia[0], C = cv[0];
#pragma unroll
        for (int k = 1; k < 4; ++k) {
            C = lae(C + ia[k], cv[k]);
            A += ia[k];
        }
        // wave inclusive scan with affine-compose
#pragma unroll
        for (int off = 1; off < 64; off <<= 1) {
            float oA = __shfl_up(A, off);
            float oC = __shfl_up(C, off);
            if (lane >= off) {
                C = lae(oC + A, C);  // uses self's OLD A
                A = oA + A;
            }
        }
        // carry into this lane = exclusive prefix applied to x_init = -inf
        float exC = __shfl_up(C, 1);
        float carry = (lane == 0) ? -INFINITY : exC;
        float cur = carry;
#pragma unroll
        for (int k = 0; k < 4; ++k) {
            cur = lae(cur + ia[k], cv[k]);
            aCur[k] = cur;
        }

        write_counts(t, v0, scur, aPrev, aCur, crow);
#pragma unroll
        for (int k = 0; k < 4; ++k) aPrev[k] = aCur[k];
    }

    if (b == 0 && lane == 63) scalar_out[0] = aPrev[3];  // alpha[0, T-1, V-1]
}

extern "C" void kernel_launch(void* const* d_in, const int* in_sizes, int n_in,
                              void* d_out, int out_size, void* d_ws, size_t ws_size,
                              hipStream_t stream) {
    const float* logits = (const float*)d_in[0];
    float* out = (float*)d_out;
    const size_t ncell = (size_t)BB * TT * VV;  // 4,194,304 cells (each C=4)

    float4* scores = (float4*)out;                    // out[0 .. 16777215]
    float4* counts = (float4*)(out + ncell * 4);      // out[16777216 .. 33554431]
    float* scalar_out = out + ncell * 8;              // out[33554432]

    k_logsoftmax<<<2048, 256, 0, stream>>>((const float4*)logits, scores, (int)ncell);
    k_dp<<<BB, 64, 0, stream>>>(scores, counts, scalar_out);
}

// Round 2
// 302.262 us; speedup vs baseline: 1.6677x; 1.6677x over previous
//
#include <hip/hip_runtime.h>
#include <math.h>

#define BB 64
#define TT 256
#define VV 256

// logaddexp, branchless, robust to -inf operands (never produces NaN from -inf pairs)
__device__ __forceinline__ float lae(float x, float y) {
    float m = fmaxf(x, y);
    float n = fminf(x, y);
    float d = (n == -INFINITY) ? -INFINITY : (n - m);
    return m + __logf(1.0f + __expf(d));
}

// Kernel 1: log_softmax over the class dim (C=4) — one float4 per cell.
__global__ void k_logsoftmax(const float4* __restrict__ lg, float4* __restrict__ sc, int n) {
    int i = blockIdx.x * blockDim.x + threadIdx.x;
    int st = gridDim.x * blockDim.x;
    for (; i < n; i += st) {
        float4 x = lg[i];
        float m = fmaxf(fmaxf(x.x, x.y), fmaxf(x.z, x.w));
        float s = __expf(x.x - m) + __expf(x.y - m) + __expf(x.z - m) + __expf(x.w - m);
        float l = m + __logf(s);
        sc[i] = make_float4(x.x - l, x.y - l, x.z - l, x.w - l);
    }
}

// Kernel 2: blocked anti-diagonal wavefront DP. One wave per batch; lane L owns
// columns v0=4L..4L+3 and at step s processes row t = s - L. Cross-lane traffic
// is a single __shfl_up per step (left neighbor boundary alpha). beta cancels
// in exp(ec - norm), so counts fuse into the forward DP (validated round 1).
__global__ void __launch_bounds__(64) k_dp(const float4* __restrict__ scores,
                                           float4* __restrict__ counts,
                                           float* __restrict__ scalar_out) {
    const int b = blockIdx.x;
    const int lane = threadIdx.x;  // 0..63
    const int v0 = lane << 2;

    const float4* __restrict__ srow = scores + ((size_t)b * TT * VV + v0);
    float4* __restrict__ crow = counts + ((size_t)b * TT * VV + v0);

    // 3-deep prefetch ring: P0/P1/P2 hold the score strip for rows s-L at s%3==0/1/2
    float4 P0[4], P1[4], P2[4];
    {
        int r; const float4* p;
        r = 0 - lane; r = r < 0 ? 0 : r; p = srow + (size_t)r * VV;
        P0[0] = p[0]; P0[1] = p[1]; P0[2] = p[2]; P0[3] = p[3];
        r = 1 - lane; r = r < 0 ? 0 : r; p = srow + (size_t)r * VV;
        P1[0] = p[0]; P1[1] = p[1]; P1[2] = p[2]; P1[3] = p[3];
        r = 2 - lane; r = r < 0 ? 0 : r; p = srow + (size_t)r * VV;
        P2[0] = p[0]; P2[1] = p[1]; P2[2] = p[2]; P2[3] = p[3];
    }

    float aPrev[4] = { -INFINITY, -INFINITY, -INFINITY, -INFINITY };
    float leftPrev = -INFINITY;  // alpha[t-1][v0-1]
    float leftCur  = -INFINITY;  // alpha[t][v0-1]

    int s = 0;

#define STEP(BUF)                                                                 \
    {                                                                             \
        const int t = s - lane;                                                   \
        const bool active = (t >= 0) && (t < TT);                                 \
        float4 c0 = BUF[0], c1 = BUF[1], c2 = BUF[2], c3 = BUF[3];                \
        { /* prefetch row t+3 (clamped; garbage rows never consumed) */           \
            int tp = t + 3; tp = tp < 0 ? 0 : tp; tp = tp > TT - 1 ? TT - 1 : tp; \
            const float4* lp = srow + (size_t)tp * VV;                            \
            BUF[0] = lp[0]; BUF[1] = lp[1]; BUF[2] = lp[2]; BUF[3] = lp[3];       \
        }                                                                         \
        float aPm1_0 = (lane == 0) ? -INFINITY : leftPrev;                        \
        float cv0 = lae(c0.x + aPrev[0], c0.z + aPm1_0);                          \
        float cv1 = lae(c1.x + aPrev[1], c1.z + aPrev[0]);                        \
        float cv2 = lae(c2.x + aPrev[2], c2.z + aPrev[1]);                        \
        float cv3 = lae(c3.x + aPrev[3], c3.z + aPrev[2]);                        \
        if (lane == 0) cv0 = c0.x + aPrev[0];   /* v==0: no sub term */           \
        if (t == 0) { /* row 0: alpha = [0, cumsum(ins[1:])] via cv = -inf */     \
            cv0 = (lane == 0) ? 0.0f : -INFINITY;                                 \
            cv1 = -INFINITY; cv2 = -INFINITY; cv3 = -INFINITY;                    \
        }                                                                         \
        float lc = (lane == 0) ? -INFINITY : leftCur;                             \
        float a0 = lae(lc + c0.y, cv0);                                           \
        float a1 = lae(a0 + c1.y, cv1);                                           \
        float a2 = lae(a1 + c2.y, cv2);                                           \
        float a3 = lae(a2 + c3.y, cv3);                                           \
        if (active) {                                                             \
            const bool valid0 = (t >= 1) && (t < TT - 1);                         \
            float4* cp = crow + (size_t)t * VV;                                   \
            float aCm1[4] = { lc, a0, a1, a2 };                                   \
            float aPm1[4] = { aPm1_0, aPrev[0], aPrev[1], aPrev[2] };             \
            float aP[4] = { aPrev[0], aPrev[1], aPrev[2], aPrev[3] };             \
            float aC[4] = { a0, a1, a2, a3 };                                     \
            float4 sv[4] = { c0, c1, c2, c3 };                                    \
            _Pragma("unroll")                                                     \
            for (int k = 0; k < 4; ++k) {                                         \
                const int v = v0 + k;                                             \
                const bool valid1 = (v >= 1) && (v < VV - 1);                     \
                float e0 = valid0 ? aP[k] + sv[k].x : -INFINITY;                  \
                float e1 = valid1 ? aCm1[k] + sv[k].y : -INFINITY;                \
                float e2 = (valid0 && valid1) ? aPm1[k] + sv[k].z : -INFINITY;    \
                float mm = fmaxf(e0, fmaxf(e1, e2));                              \
                float4 o = make_float4(0.0f, 0.0f, 0.0f, 0.0f);                   \
                if (mm != -INFINITY) {                                            \
                    float w0 = __expf(e0 - mm);                                   \
                    float w1 = __expf(e1 - mm);                                   \
                    float w2 = __expf(e2 - mm);                                   \
                    float r = 1.0f / (w0 + w1 + w2);                              \
                    o = make_float4(w0 * r, w1 * r, w2 * r, 0.0f);                \
                }                                                                 \
                cp[k] = o;                                                        \
            }                                                                     \
            (void)aC;                                                             \
            if ((t == TT - 1) && (lane == 63) && (b == 0)) scalar_out[0] = a3;    \
        }                                                                         \
        aPrev[0] = a0; aPrev[1] = a1; aPrev[2] = a2; aPrev[3] = a3;               \
        leftPrev = leftCur;                                                       \
        leftCur = __shfl_up(a3, 1);                                               \
        ++s;                                                                      \
    }

    // 321 steps >= 319 needed (lane 63 finishes row 255 at s=318); 3x unrolled
    // so the prefetch ring index is compile-time static (no scratch).
#pragma unroll 1
    for (int it = 0; it < 107; ++it) {
        STEP(P0);
        STEP(P1);
        STEP(P2);
    }
#undef STEP
}

extern "C" void kernel_launch(void* const* d_in, const int* in_sizes, int n_in,
                              void* d_out, int out_size, void* d_ws, size_t ws_size,
                              hipStream_t stream) {
    const float* logits = (const float*)d_in[0];
    float* out = (float*)d_out;
    const size_t ncell = (size_t)BB * TT * VV;  // 4,194,304 cells (each C=4)

    float4* scores = (float4*)out;                    // output 0: log_softmax
    float4* counts = (float4*)(out + ncell * 4);      // output 1: expected_counts
    float* scalar_out = out + ncell * 8;              // output 2: alpha[0,-1,-1]

    k_logsoftmax<<<2048, 256, 0, stream>>>((const float4*)logits, scores, (int)ncell);
    k_dp<<<BB, 64, 0, stream>>>(scores, counts, scalar_out);
}

// Round 3
// 276.433 us; speedup vs baseline: 1.8236x; 1.0934x over previous
//
#include <hip/hip_runtime.h>
#include <math.h>

#define BB 64
#define TT 256
#define VV 256
#define SLABS 321   // s = t + v/4 in [0,318]; +2 pad so clamped prefetch stays in-bounds

// logaddexp, branchless, robust to -inf operands
__device__ __forceinline__ float lae(float x, float y) {
    float m = fmaxf(x, y);
    float n = fminf(x, y);
    float d = (n == -INFINITY) ? -INFINITY : (n - m);
    return m + __logf(1.0f + __expf(d));
}

// Kernel 1: log_softmax over C=4; writes canonical scores (output 0) and,
// optionally, a diagonal-major copy D[b][s][v] (s = t + v/4) for k_dp.
__global__ void k_prep(const float4* __restrict__ lg, float4* __restrict__ sc,
                       float4* __restrict__ Ds, int writeDiag, int n) {
    int i = blockIdx.x * blockDim.x + threadIdx.x;
    int st = gridDim.x * blockDim.x;
    for (; i < n; i += st) {
        float4 x = lg[i];
        float m = fmaxf(fmaxf(x.x, x.y), fmaxf(x.z, x.w));
        float s = __expf(x.x - m) + __expf(x.y - m) + __expf(x.z - m) + __expf(x.w - m);
        float l = m + __logf(s);
        float4 r = make_float4(x.x - l, x.y - l, x.z - l, x.w - l);
        sc[i] = r;
        if (writeDiag) {
            int b = i >> 16;
            int rr = i & 65535;
            int t = rr >> 8;
            int v = rr & 255;
            Ds[(((size_t)b * SLABS + t + (v >> 2)) << 8) + v] = r;
        }
    }
}

// Kernel 3: permute diag-layout counts back to (b,t,v) output layout.
__global__ void k_perm(const float4* __restrict__ Dc, float4* __restrict__ out, int n) {
    int i = blockIdx.x * blockDim.x + threadIdx.x;
    int st = gridDim.x * blockDim.x;
    for (; i < n; i += st) {
        int b = i >> 16;
        int rr = i & 65535;
        int t = rr >> 8;
        int v = rr & 255;
        out[i] = Dc[(((size_t)b * SLABS + t + (v >> 2)) << 8) + v];
    }
}

// Kernel 2: anti-diagonal wavefront DP with dense (diag-layout) loads; one wave
// per batch, lane L owns columns 4L..4L+3, step s processes row t = s - L.
// For interior cells norm == alpha, so counts = exp(e - alpha): 3 exps per cell.
template <bool DIAG_STORE>
__global__ void __launch_bounds__(64) k_dp_diag(const float4* __restrict__ Ds,
                                                float4* __restrict__ Dc,
                                                float4* __restrict__ counts,
                                                float* __restrict__ scalar_out) {
    const int b = blockIdx.x;
    const int lane = threadIdx.x;  // 0..63
    const int v0 = lane << 2;

    const float4* __restrict__ Dsb = Ds + (((size_t)b * SLABS) << 8) + v0;
    float4* __restrict__ Dcb = DIAG_STORE ? (Dc + (((size_t)b * SLABS) << 8) + v0) : nullptr;
    float4* __restrict__ crow = DIAG_STORE ? nullptr : (counts + (size_t)b * TT * VV + v0);

    // 4-deep prefetch ring over diag slabs
    float4 P0[4], P1[4], P2[4], P3[4];
    {
        const float4* p;
        p = Dsb;                  P0[0]=p[0]; P0[1]=p[1]; P0[2]=p[2]; P0[3]=p[3];
        p = Dsb + (1 << 8);       P1[0]=p[0]; P1[1]=p[1]; P1[2]=p[2]; P1[3]=p[3];
        p = Dsb + (2 << 8);       P2[0]=p[0]; P2[1]=p[1]; P2[2]=p[2]; P2[3]=p[3];
        p = Dsb + (3 << 8);       P3[0]=p[0]; P3[1]=p[1]; P3[2]=p[2]; P3[3]=p[3];
    }

    float aPrev[4] = { -INFINITY, -INFINITY, -INFINITY, -INFINITY };
    float leftPrev = -INFINITY;  // alpha[t-1][v0-1]
    float leftCur  = -INFINITY;  // alpha[t][v0-1]

    int s = 0;

#define STEP(BUF)                                                                 \
    {                                                                             \
        const int t = s - lane;                                                   \
        float4 c0 = BUF[0], c1 = BUF[1], c2 = BUF[2], c3 = BUF[3];                \
        { /* prefetch slab s+4 (clamped; pad slabs never consumed as real data) */\
            int sp = s + 4; sp = sp > SLABS - 1 ? SLABS - 1 : sp;                 \
            const float4* lp = Dsb + ((size_t)sp << 8);                           \
            BUF[0] = lp[0]; BUF[1] = lp[1]; BUF[2] = lp[2]; BUF[3] = lp[3];       \
        }                                                                         \
        float aPm1_0 = (lane == 0) ? -INFINITY : leftPrev;                        \
        float cv0 = lae(c0.x + aPrev[0], c0.z + aPm1_0);                          \
        float cv1 = lae(c1.x + aPrev[1], c1.z + aPrev[0]);                        \
        float cv2 = lae(c2.x + aPrev[2], c2.z + aPrev[1]);                        \
        float cv3 = lae(c3.x + aPrev[3], c3.z + aPrev[2]);                        \
        if (lane == 0) cv0 = c0.x + aPrev[0];   /* v==0: no sub term */           \
        if (t == 0) { /* row 0: alpha = [0, cumsum(ins[1:])] */                   \
            cv0 = (lane == 0) ? 0.0f : -INFINITY;                                 \
            cv1 = -INFINITY; cv2 = -INFINITY; cv3 = -INFINITY;                    \
        }                                                                         \
        float lc = (lane == 0) ? -INFINITY : leftCur;                             \
        float a0 = lae(lc + c0.y, cv0);                                           \
        float a1 = lae(a0 + c1.y, cv1);                                           \
        float a2 = lae(a1 + c2.y, cv2);                                           \
        float a3 = lae(a2 + c3.y, cv3);                                           \
        const bool active = (t >= 0) && (t < TT);                                 \
        if (DIAG_STORE || active) {                                               \
            const bool tE = (t <= 0) | (t >= TT - 1);                             \
            float aCm1[4] = { lc, a0, a1, a2 };                                   \
            float aPm1[4] = { aPm1_0, aPrev[0], aPrev[1], aPrev[2] };             \
            float aP[4]   = { aPrev[0], aPrev[1], aPrev[2], aPrev[3] };           \
            float aA[4]   = { a0, a1, a2, a3 };                                   \
            float4 sv[4]  = { c0, c1, c2, c3 };                                   \
            float4* cp = DIAG_STORE ? (Dcb + ((size_t)s << 8))                    \
                                    : (crow + (size_t)t * VV);                    \
            _Pragma("unroll")                                                     \
            for (int k = 0; k < 4; ++k) {                                         \
                const bool vE = (k == 0 && lane == 0) || (k == 3 && lane == 63);  \
                float w0 = __expf(aP[k]   + sv[k].x - aA[k]);                     \
                float w1 = __expf(aCm1[k] + sv[k].y - aA[k]);                     \
                float w2 = __expf(aPm1[k] + sv[k].z - aA[k]);                     \
                float4 o;                                                         \
                o.x = tE ? 0.0f : (vE ? 1.0f : w0);                               \
                o.y = vE ? 0.0f : (tE ? 1.0f : w1);                               \
                o.z = (tE || vE) ? 0.0f : w2;                                     \
                o.w = 0.0f;                                                       \
                cp[k] = o;                                                        \
            }                                                                     \
        }                                                                         \
        if ((t == TT - 1) && (lane == 63) && (b == 0)) scalar_out[0] = a3;        \
        aPrev[0] = a0; aPrev[1] = a1; aPrev[2] = a2; aPrev[3] = a3;               \
        leftPrev = leftCur;                                                       \
        leftCur = __shfl_up(a3, 1);                                               \
        ++s;                                                                      \
    }

    // 320 steps >= 319 needed (lane 63 finishes row 255 at s=318); 4x unrolled
    // so the ring index is compile-time static (no scratch).
#pragma unroll 1
    for (int it = 0; it < 80; ++it) {
        STEP(P0);
        STEP(P1);
        STEP(P2);
        STEP(P3);
    }
#undef STEP
}

// Fallback (round-2 kernel, scattered loads+stores) for tiny ws_size.
__global__ void __launch_bounds__(64) k_dp_legacy(const float4* __restrict__ scores,
                                                  float4* __restrict__ counts,
                                                  float* __restrict__ scalar_out) {
    const int b = blockIdx.x;
    const int lane = threadIdx.x;
    const int v0 = lane << 2;
    const float4* __restrict__ srow = scores + ((size_t)b * TT * VV + v0);
    float4* __restrict__ crow = counts + ((size_t)b * TT * VV + v0);
    float4 P0[4], P1[4], P2[4];
    {
        int r; const float4* p;
        r = 0 - lane; r = r < 0 ? 0 : r; p = srow + (size_t)r * VV;
        P0[0]=p[0]; P0[1]=p[1]; P0[2]=p[2]; P0[3]=p[3];
        r = 1 - lane; r = r < 0 ? 0 : r; p = srow + (size_t)r * VV;
        P1[0]=p[0]; P1[1]=p[1]; P1[2]=p[2]; P1[3]=p[3];
        r = 2 - lane; r = r < 0 ? 0 : r; p = srow + (size_t)r * VV;
        P2[0]=p[0]; P2[1]=p[1]; P2[2]=p[2]; P2[3]=p[3];
    }
    float aPrev[4] = { -INFINITY, -INFINITY, -INFINITY, -INFINITY };
    float leftPrev = -INFINITY, leftCur = -INFINITY;
    int s = 0;
#define STEPL(BUF)                                                                \
    {                                                                             \
        const int t = s - lane;                                                   \
        const bool active = (t >= 0) && (t < TT);                                 \
        float4 c0 = BUF[0], c1 = BUF[1], c2 = BUF[2], c3 = BUF[3];                \
        {                                                                         \
            int tp = t + 3; tp = tp < 0 ? 0 : tp; tp = tp > TT - 1 ? TT - 1 : tp; \
            const float4* lp = srow + (size_t)tp * VV;                            \
            BUF[0]=lp[0]; BUF[1]=lp[1]; BUF[2]=lp[2]; BUF[3]=lp[3];               \
        }                                                                         \
        float aPm1_0 = (lane == 0) ? -INFINITY : leftPrev;                        \
        float cv0 = lae(c0.x + aPrev[0], c0.z + aPm1_0);                          \
        float cv1 = lae(c1.x + aPrev[1], c1.z + aPrev[0]);                        \
        float cv2 = lae(c2.x + aPrev[2], c2.z + aPrev[1]);                        \
        float cv3 = lae(c3.x + aPrev[3], c3.z + aPrev[2]);                        \
        if (lane == 0) cv0 = c0.x + aPrev[0];                                     \
        if (t == 0) {                                                             \
            cv0 = (lane == 0) ? 0.0f : -INFINITY;                                 \
            cv1 = -INFINITY; cv2 = -INFINITY; cv3 = -INFINITY;                    \
        }                                                                         \
        float lc = (lane == 0) ? -INFINITY : leftCur;                             \
        float a0 = lae(lc + c0.y, cv0);                                           \
        float a1 = lae(a0 + c1.y, cv1);                                           \
        float a2 = lae(a1 + c2.y, cv2);                                           \
        float a3 = lae(a2 + c3.y, cv3);                                           \
        if (active) {                                                             \
            const bool tE = (t == 0) | (t == TT - 1);                             \
            float aCm1[4] = { lc, a0, a1, a2 };                                   \
            float aPm1[4] = { aPm1_0, aPrev[0], aPrev[1], aPrev[2] };             \
            float aP[4]   = { aPrev[0], aPrev[1], aPrev[2], aPrev[3] };           \
            float aA[4]   = { a0, a1, a2, a3 };                                   \
            float4 sv[4]  = { c0, c1, c2, c3 };                                   \
            float4* cp = crow + (size_t)t * VV;                                   \
            _Pragma("unroll")                                                     \
            for (int k = 0; k < 4; ++k) {                                         \
                const bool vE = (k == 0 && lane == 0) || (k == 3 && lane == 63);  \
                float w0 = __expf(aP[k]   + sv[k].x - aA[k]);                     \
                float w1 = __expf(aCm1[k] + sv[k].y - aA[k]);                     \
                float w2 = __expf(aPm1[k] + sv[k].z - aA[k]);                     \
                float4 o;                                                         \
                o.x = tE ? 0.0f : (vE ? 1.0f : w0);                               \
                o.y = vE ? 0.0f : (tE ? 1.0f : w1);                               \
                o.z = (tE || vE) ? 0.0f : w2;                                     \
                o.w = 0.0f;                                                       \
                cp[k] = o;                                                        \
            }                                                                     \
            if ((t == TT - 1) && (lane == 63) && (b == 0)) scalar_out[0] = a3;    \
        }                                                                         \
        aPrev[0]=a0; aPrev[1]=a1; aPrev[2]=a2; aPrev[3]=a3;                       \
        leftPrev = leftCur;                                                       \
        leftCur = __shfl_up(a3, 1);                                               \
        ++s;                                                                      \
    }
#pragma unroll 1
    for (int it = 0; it < 107; ++it) { STEPL(P0); STEPL(P1); STEPL(P2); }
#undef STEPL
}

extern "C" void kernel_launch(void* const* d_in, const int* in_sizes, int n_in,
                              void* d_out, int out_size, void* d_ws, size_t ws_size,
                              hipStream_t stream) {
    const float* logits = (const float*)d_in[0];
    float* out = (float*)d_out;
    const size_t ncell = (size_t)BB * TT * VV;  // 4,194,304 cells (each C=4)

    float4* scores = (float4*)out;                    // output 0: log_softmax
    float4* counts = (float4*)(out + ncell * 4);      // output 1: expected_counts
    float* scalar_out = out + ncell * 8;              // output 2: alpha[0,-1,-1]

    const size_t dbuf = ((size_t)BB * SLABS) << 12;   // 84,148,224 B per diag buffer
    float4* Ds = (float4*)d_ws;
    float4* Dc = (float4*)((char*)d_ws + dbuf);

    if (ws_size >= 2 * dbuf) {
        k_prep<<<2048, 256, 0, stream>>>((const float4*)logits, scores, Ds, 1, (int)ncell);
        k_dp_diag<true><<<BB, 64, 0, stream>>>(Ds, Dc, counts, scalar_out);
        k_perm<<<2048, 256, 0, stream>>>(Dc, counts, (int)ncell);
    } else if (ws_size >= dbuf) {
        k_prep<<<2048, 256, 0, stream>>>((const float4*)logits, scores, Ds, 1, (int)ncell);
        k_dp_diag<false><<<BB, 64, 0, stream>>>(Ds, nullptr, counts, scalar_out);
    } else {
        k_prep<<<2048, 256, 0, stream>>>((const float4*)logits, scores, nullptr, 0, (int)ncell);
        k_dp_legacy<<<BB, 64, 0, stream>>>(scores, counts, scalar_out);
    }
}